// Round 3
// baseline (96.787 us; speedup 1.0000x reference)
//
#include <hip/hip_runtime.h>

#define BB 8            // batches
#define NN 8192         // points per set
#define BLOCK 256
#define QPT 16                   // queries per thread
#define QPB (BLOCK * QPT)        // 4096 queries per block
#define QB (NN / QPB)            // 2 query-blocks per (dir, b)
#define TQ (2 * BB * NN)         // 131072 total queries

// Two transformed refs per 32B: a = (-2y0,-2y1,-2y2, yy), b likewise.
// Inner: per (query, 2 refs): 6 v_fma_f32 + 1 v_min3_f32 = 3.5 ops/pair.
struct __align__(16) RefPair {
  float4 a, b;
};

template <int CHUNK>
__global__ __launch_bounds__(BLOCK, 4) void chamfer_partial(
    const float* __restrict__ preds, const float* __restrict__ gts,
    float* __restrict__ partial, int R) {
  constexpr int NPAIR = CHUNK / 2;
  __shared__ RefPair lref[NPAIR];

  int bi = blockIdx.x;
  int r = bi % R;
  int qb = (bi / R) % QB;
  int b = (bi / (R * QB)) % BB;
  int dir = bi / (R * QB * BB);

  // dir 0: queries = preds, refs = gts; dir 1: swapped.
  const float* qry = (dir == 0) ? preds : gts;
  const float* ref = (dir == 0) ? gts : preds;

  // ---- stage transformed ref pairs into LDS ----
  const float* rbase = ref + ((size_t)b * NN + (size_t)r * CHUNK) * 3;
  for (int j = threadIdx.x; j < NPAIR; j += BLOCK) {
    float a0 = rbase[j * 6 + 0], a1 = rbase[j * 6 + 1], a2 = rbase[j * 6 + 2];
    float c0 = rbase[j * 6 + 3], c1 = rbase[j * 6 + 4], c2 = rbase[j * 6 + 5];
    RefPair rp;
    rp.a = make_float4(-2.f * a0, -2.f * a1, -2.f * a2,
                       a0 * a0 + a1 * a1 + a2 * a2);
    rp.b = make_float4(-2.f * c0, -2.f * c1, -2.f * c2,
                       c0 * c0 + c1 * c1 + c2 * c2);
    lref[j] = rp;
  }
  __syncthreads();

  // ---- this thread's 16 query points (48 contiguous floats) ----
  int q0 = qb * QPB + threadIdx.x * QPT;
  const float* qbase = qry + ((size_t)b * NN + q0) * 3;
  float x0[QPT], x1[QPT], x2[QPT], xx[QPT], mn[QPT];
#pragma unroll
  for (int k = 0; k < QPT; ++k) {
    x0[k] = qbase[k * 3 + 0];
    x1[k] = qbase[k * 3 + 1];
    x2[k] = qbase[k * 3 + 2];
    xx[k] = x0[k] * x0[k] + x1[k] * x1[k] + x2[k] * x2[k];
    mn[k] = 3.4e38f;
  }

  // ---- inner loop: per 2 refs per query: 6 fma + 1 min3 ----
#pragma unroll 2
  for (int j = 0; j < NPAIR; ++j) {
    float4 ra = lref[j].a;  // broadcast reads, conflict-free
    float4 rb = lref[j].b;
#pragma unroll
    for (int k = 0; k < QPT; ++k) {
      float ta = fmaf(x0[k], ra.x, fmaf(x1[k], ra.y, fmaf(x2[k], ra.z, ra.w)));
      float tb = fmaf(x0[k], rb.x, fmaf(x1[k], rb.y, fmaf(x2[k], rb.z, rb.w)));
      mn[k] = fminf(mn[k], fminf(ta, tb));  // -> v_min3_f32
    }
  }

  // ---- write partial mins (xx folded; constant across R so min-safe) ----
  size_t gq = ((size_t)dir * BB + b) * NN + q0;
  float* out = partial + (size_t)r * TQ + gq;
#pragma unroll
  for (int k4 = 0; k4 < QPT; k4 += 4) {
    float4 res = make_float4(mn[k4 + 0] + xx[k4 + 0], mn[k4 + 1] + xx[k4 + 1],
                             mn[k4 + 2] + xx[k4 + 2], mn[k4 + 3] + xx[k4 + 3]);
    *(float4*)(out + k4) = res;
  }
}

// K2: per query, min over R slices; deterministic block-tree sum.
__global__ __launch_bounds__(BLOCK) void chamfer_reduce(
    const float* __restrict__ partial, float* __restrict__ bsums, int R) {
  int q = blockIdx.x * BLOCK + threadIdx.x;
  float m = 3.4e38f;
  for (int r = 0; r < R; ++r) m = fminf(m, partial[(size_t)r * TQ + q]);
  __shared__ float s[BLOCK];
  s[threadIdx.x] = m;
  __syncthreads();
  for (int o = BLOCK / 2; o > 0; o >>= 1) {
    if (threadIdx.x < o) s[threadIdx.x] += s[threadIdx.x + o];
    __syncthreads();
  }
  if (threadIdx.x == 0) bsums[blockIdx.x] = s[0];
}

// K3: deterministic single-block final sum.
__global__ __launch_bounds__(BLOCK) void chamfer_final(
    const float* __restrict__ bsums, float* __restrict__ out, int n) {
  float v = 0.f;
  for (int i = threadIdx.x; i < n; i += BLOCK) v += bsums[i];
  __shared__ float s[BLOCK];
  s[threadIdx.x] = v;
  __syncthreads();
  for (int o = BLOCK / 2; o > 0; o >>= 1) {
    if (threadIdx.x < o) s[threadIdx.x] += s[threadIdx.x + o];
    __syncthreads();
  }
  if (threadIdx.x == 0) out[0] = s[0];
}

extern "C" void kernel_launch(void* const* d_in, const int* in_sizes, int n_in,
                              void* d_out, int out_size, void* d_ws,
                              size_t ws_size, hipStream_t stream) {
  const float* preds = (const float*)d_in[0];
  const float* gts = (const float*)d_in[1];
  float* out = (float*)d_out;
  float* partial = (float*)d_ws;

  // pick R (ref-chunk split) by available workspace: need R*TQ*4 + bsums
  int R;
  size_t need32 = (size_t)32 * TQ * 4 + 4096;
  size_t need16 = (size_t)16 * TQ * 4 + 4096;
  size_t need8 = (size_t)8 * TQ * 4 + 4096;
  if (ws_size >= need32)
    R = 32;
  else if (ws_size >= need16)
    R = 16;
  else if (ws_size >= need8)
    R = 8;
  else
    R = 4;

  float* bsums = partial + (size_t)R * TQ;
  int nq_blocks = TQ / BLOCK;  // 512

  int grid1 = 2 * BB * QB * R;
  switch (R) {
    case 32:
      chamfer_partial<NN / 32><<<grid1, BLOCK, 0, stream>>>(preds, gts, partial, R);
      break;
    case 16:
      chamfer_partial<NN / 16><<<grid1, BLOCK, 0, stream>>>(preds, gts, partial, R);
      break;
    case 8:
      chamfer_partial<NN / 8><<<grid1, BLOCK, 0, stream>>>(preds, gts, partial, R);
      break;
    default:
      chamfer_partial<NN / 4><<<grid1, BLOCK, 0, stream>>>(preds, gts, partial, R);
      break;
  }
  chamfer_reduce<<<nq_blocks, BLOCK, 0, stream>>>(partial, bsums, R);
  chamfer_final<<<1, BLOCK, 0, stream>>>(bsums, out, nq_blocks);
}

// Round 4
// 58.009 us; speedup vs baseline: 1.6685x; 1.6685x over previous
//
#include <hip/hip_runtime.h>

typedef _Float16 f16;
typedef f16 half8 __attribute__((ext_vector_type(8)));
typedef float f32x16 __attribute__((ext_vector_type(16)));

#define BB 8
#define NN 8192
#define SETPTS (BB * NN)   // 65536 points per set
#define NPTS (2 * SETPTS)  // 131072 total points
#define TQ NPTS            // total queries (each point queries the other set)

// ---------------- prep: build fp16-split MFMA operands ----------------
// A-rep (point as query):  per coord (h,l,h,l); tail (1,1,0,0)
// B-rep (point as ref):    per coord (H,H,L,L) of -2y; tail (yy_h,yy_l,0,0)
// products per coord: hH + lH + hL + lL = (h+l)(H+L)  [exact in fp32 accum]
__global__ __launch_bounds__(256) void chamfer_prep(
    const float* __restrict__ preds, const float* __restrict__ gts,
    float* __restrict__ yy, half8* __restrict__ Aq, half8* __restrict__ Bq) {
  int idx = blockIdx.x * 256 + threadIdx.x;  // 0..NPTS-1
  int s = idx >> 16;                         // set: 0=preds, 1=gts
  int off = idx & (SETPTS - 1);
  const float* src = s ? gts : preds;
  float x0 = src[off * 3 + 0], x1 = src[off * 3 + 1], x2 = src[off * 3 + 2];

  f16 h0 = (f16)x0; f16 l0 = (f16)(x0 - (float)h0);
  f16 h1 = (f16)x1; f16 l1 = (f16)(x1 - (float)h1);
  f16 h2 = (f16)x2; f16 l2 = (f16)(x2 - (float)h2);

  float Y0 = -2.f * x0, Y1 = -2.f * x1, Y2 = -2.f * x2;
  f16 H0 = (f16)Y0; f16 L0 = (f16)(Y0 - (float)H0);
  f16 H1 = (f16)Y1; f16 L1 = (f16)(Y1 - (float)H1);
  f16 H2 = (f16)Y2; f16 L2 = (f16)(Y2 - (float)H2);

  float yv = x0 * x0 + x1 * x1 + x2 * x2;
  f16 yh = (f16)yv; f16 yl = (f16)(yv - (float)yh);

  f16 one = (f16)1.f, zz = (f16)0.f;
  half8 A0 = {h0, l0, h0, l0, h1, l1, h1, l1};
  half8 A1 = {h2, l2, h2, l2, one, one, zz, zz};
  half8 B0 = {H0, H0, L0, L0, H1, H1, L1, L1};
  half8 B1 = {H2, H2, L2, L2, yh, yl, zz, zz};

  Aq[idx * 2 + 0] = A0; Aq[idx * 2 + 1] = A1;
  Bq[idx * 2 + 0] = B0; Bq[idx * 2 + 1] = B1;
  yy[idx] = yv;
}

// ---------------- main: MFMA distance tiles + running per-query min ------
// Wave: 64 queries (2 A-frags). Block: 4 waves = 256 queries.
// Grid: dir(2) x b(8) x qb(32) x refhalf(2) = 1024 blocks.
// A layout (32x32x16): lane holds row=lane&31, k=(lane>>5)*8+e. B symmetric.
// C/D layout (verified): col=lane&31, row=(reg&3)+8*(reg>>2)+4*(lane>>5).
__global__ __launch_bounds__(256, 4) void chamfer_mfma(
    const half8* __restrict__ Aq, const half8* __restrict__ Bq,
    float* __restrict__ partial) {
  int bi = blockIdx.x;
  int r = bi & 1;
  int qb = (bi >> 1) & 31;
  int b = (bi >> 6) & 7;
  int dir = bi >> 9;

  int tid = threadIdx.x;
  int wid = tid >> 6;
  int l = tid & 63;
  int l31 = l & 31;
  int lh = l >> 5;

  // queries come from set `dir`, refs from set `1-dir`
  const half8* Ap =
      Aq + ((size_t)(dir * BB + b) * NN + qb * 256 + wid * 64) * 2;
  half8 a0 = Ap[(l31) * 2 + lh];
  half8 a1 = Ap[(32 + l31) * 2 + lh];

  const half8* Bl =
      Bq + ((size_t)((1 - dir) * BB + b) * NN + r * 4096) * 2 + l31 * 2 + lh;

  f32x16 zero;
#pragma unroll
  for (int i = 0; i < 16; ++i) zero[i] = 0.f;
  f32x16 run0, run1;
#pragma unroll
  for (int i = 0; i < 16; ++i) { run0[i] = 3.4e38f; run1[i] = 3.4e38f; }

  half8 bcur = Bl[0];
#pragma unroll 2
  for (int step = 0; step < 128; ++step) {
    half8 bnext = Bl[(size_t)(((step + 1) & 127) * 64)];  // prefetch (wraps)
    f32x16 o0 = __builtin_amdgcn_mfma_f32_32x32x16_f16(a0, bcur, zero, 0, 0, 0);
    f32x16 o1 = __builtin_amdgcn_mfma_f32_32x32x16_f16(a1, bcur, zero, 0, 0, 0);
#pragma unroll
    for (int i = 0; i < 16; ++i) {
      run0[i] = fminf(run0[i], o0[i]);
      run1[i] = fminf(run1[i], o1[i]);
    }
    bcur = bnext;
  }

  // min over ref-columns (32 lanes within each half), then write per-query
  size_t qflat = (size_t)(dir * BB + b) * NN + qb * 256 + wid * 64;
  float* pr = partial + (size_t)r * TQ + qflat;
#pragma unroll
  for (int i = 0; i < 16; ++i) {
    float v0 = run0[i], v1 = run1[i];
    v0 = fminf(v0, __shfl_xor(v0, 1));  v1 = fminf(v1, __shfl_xor(v1, 1));
    v0 = fminf(v0, __shfl_xor(v0, 2));  v1 = fminf(v1, __shfl_xor(v1, 2));
    v0 = fminf(v0, __shfl_xor(v0, 4));  v1 = fminf(v1, __shfl_xor(v1, 4));
    v0 = fminf(v0, __shfl_xor(v0, 8));  v1 = fminf(v1, __shfl_xor(v1, 8));
    v0 = fminf(v0, __shfl_xor(v0, 16)); v1 = fminf(v1, __shfl_xor(v1, 16));
    int row = (i & 3) + 8 * (i >> 2) + 4 * lh;
    if (l31 == i) {
      pr[row] = v0;
      pr[32 + row] = v1;
    }
  }
}

// ---------------- combine: min over 2 ref-halves + xx, block sum ---------
__global__ __launch_bounds__(256) void chamfer_combine(
    const float* __restrict__ partial, const float* __restrict__ yy,
    float* __restrict__ bsums) {
  int q = blockIdx.x * 256 + threadIdx.x;
  float m = fminf(partial[q], partial[TQ + q]) + yy[q];
  __shared__ float s[256];
  s[threadIdx.x] = m;
  __syncthreads();
  for (int o = 128; o > 0; o >>= 1) {
    if (threadIdx.x < o) s[threadIdx.x] += s[threadIdx.x + o];
    __syncthreads();
  }
  if (threadIdx.x == 0) bsums[blockIdx.x] = s[0];
}

__global__ __launch_bounds__(256) void chamfer_final(
    const float* __restrict__ bsums, float* __restrict__ out, int n) {
  float v = 0.f;
  for (int i = threadIdx.x; i < n; i += 256) v += bsums[i];
  __shared__ float s[256];
  s[threadIdx.x] = v;
  __syncthreads();
  for (int o = 128; o > 0; o >>= 1) {
    if (threadIdx.x < o) s[threadIdx.x] += s[threadIdx.x + o];
    __syncthreads();
  }
  if (threadIdx.x == 0) out[0] = s[0];
}

extern "C" void kernel_launch(void* const* d_in, const int* in_sizes, int n_in,
                              void* d_out, int out_size, void* d_ws,
                              size_t ws_size, hipStream_t stream) {
  const float* preds = (const float*)d_in[0];
  const float* gts = (const float*)d_in[1];
  float* out = (float*)d_out;

  // ws layout (floats): partial[2*TQ] | bsums[1024] | yy[NPTS] | Aq | Bq
  float* partial = (float*)d_ws;
  float* bsums = partial + 2 * (size_t)TQ;
  float* yy = bsums + 1024;
  half8* Aq = (half8*)(yy + NPTS);        // NPTS*2 half8 (16B-aligned offset)
  half8* Bq = Aq + (size_t)NPTS * 2;

  chamfer_prep<<<NPTS / 256, 256, 0, stream>>>(preds, gts, yy, Aq, Bq);
  chamfer_mfma<<<1024, 256, 0, stream>>>(Aq, Bq, partial);
  chamfer_combine<<<TQ / 256, 256, 0, stream>>>(partial, yy, bsums);
  chamfer_final<<<1, 256, 0, stream>>>(bsums, out, TQ / 256);
}